// Round 1
// baseline (2273.279 us; speedup 1.0000x reference)
//
#include <hip/hip_runtime.h>
#include <hip/hip_bf16.h>
#include <math.h>

#define NTOK 8192
#define DM   1024
#define NE   16
#define HD   4096
#define CAP  640

typedef unsigned short ushort_t;

__device__ __forceinline__ ushort_t f2bf(float f) {
  union { float f; unsigned int i; } v; v.f = f;
  unsigned int x = v.i;
  unsigned int r = (x + 0x7fffu + ((x >> 16) & 1u)) >> 16;
  return (ushort_t)r;
}
__device__ __forceinline__ float bf2f(ushort_t u) {
  union { unsigned int i; float f; } v; v.i = ((unsigned int)u) << 16; return v.f;
}

// ---------------- router logits + softmax: one wave per token ----------------
__global__ __launch_bounds__(256) void k_router(const float* __restrict__ x,
                                                const float* __restrict__ Wr,
                                                float* __restrict__ probs) {
  int wave = threadIdx.x >> 6, lane = threadIdx.x & 63;
  int tok = blockIdx.x * 4 + wave;
  const float* xr = x + (size_t)tok * DM;
  float acc[NE];
#pragma unroll
  for (int e = 0; e < NE; ++e) acc[e] = 0.f;
  for (int d = lane; d < DM; d += 64) {
    float xv = xr[d];
    const float* w = Wr + (size_t)d * NE;
#pragma unroll
    for (int e = 0; e < NE; ++e) acc[e] = fmaf(xv, w[e], acc[e]);
  }
#pragma unroll
  for (int off = 32; off >= 1; off >>= 1) {
#pragma unroll
    for (int e = 0; e < NE; ++e) acc[e] += __shfl_xor(acc[e], off, 64);
  }
  float m = acc[0];
#pragma unroll
  for (int e = 1; e < NE; ++e) m = fmaxf(m, acc[e]);
  float s = 0.f;
#pragma unroll
  for (int e = 0; e < NE; ++e) { acc[e] = expf(acc[e] - m); s += acc[e]; }
  if (lane < NE) probs[(size_t)tok * NE + lane] = acc[lane] / s;
}

// ---------------- sinkhorn: row-normalize + per-block column partial sums ----
__global__ __launch_bounds__(256) void k_rownorm(float* __restrict__ probs,
                                                 float* __restrict__ partial) {
  int tok = blockIdx.x * 256 + threadIdx.x;
  int lane = threadIdx.x & 63, wave = threadIdx.x >> 6;
  float* row = probs + (size_t)tok * NE;
  float p[NE]; float rs = 0.f;
#pragma unroll
  for (int e = 0; e < NE; ++e) { p[e] = row[e]; rs += p[e]; }
#pragma unroll
  for (int e = 0; e < NE; ++e) { p[e] = p[e] / rs; row[e] = p[e]; }
#pragma unroll
  for (int off = 32; off >= 1; off >>= 1) {
#pragma unroll
    for (int e = 0; e < NE; ++e) p[e] += __shfl_xor(p[e], off, 64);
  }
  __shared__ float wsum[4][NE];
  if (lane == 0) {
#pragma unroll
    for (int e = 0; e < NE; ++e) wsum[wave][e] = p[e];
  }
  __syncthreads();
  if (threadIdx.x < NE)
    partial[blockIdx.x * NE + threadIdx.x] =
        wsum[0][threadIdx.x] + wsum[1][threadIdx.x] + wsum[2][threadIdx.x] + wsum[3][threadIdx.x];
}

__global__ void k_colreduce(const float* __restrict__ partial, float* __restrict__ cs) {
  int e = threadIdx.x;
  if (e < NE) {
    float s = 0.f;
    for (int b = 0; b < 32; ++b) s += partial[b * NE + e];
    cs[e] = s;
  }
}

__global__ __launch_bounds__(256) void k_colscale(float* __restrict__ probs,
                                                  const float* __restrict__ cs) {
  int tok = blockIdx.x * 256 + threadIdx.x;
  float* row = probs + (size_t)tok * NE;
#pragma unroll
  for (int e = 0; e < NE; ++e) row[e] = row[e] / cs[e] * 512.0f;
}

// ---------------- top-2 + weight renorm ----------------
__global__ __launch_bounds__(256) void k_topk(const float* __restrict__ probs,
                                              int* __restrict__ eidx,
                                              float* __restrict__ ew) {
  int tok = blockIdx.x * 256 + threadIdx.x;
  const float* row = probs + (size_t)tok * NE;
  float v0 = -1e30f, v1 = -1e30f; int e0 = 0, e1 = 0;
#pragma unroll
  for (int e = 0; e < NE; ++e) {
    float v = row[e];
    if (v > v0) { v1 = v0; e1 = e0; v0 = v; e0 = e; }
    else if (v > v1) { v1 = v; e1 = e; }
  }
  float s = v0 + v1;
  eidx[tok * 2] = e0; eidx[tok * 2 + 1] = e1;
  ew[tok * 2] = v0 / s; ew[tok * 2 + 1] = v1 / s;
}

// ------------- sequential (t,k)-order slot allocation: one block per expert -------------
__global__ __launch_bounds__(256) void k_scan(const int* __restrict__ eidx,
                                              const float* __restrict__ ew,
                                              int* __restrict__ slot_tok,
                                              float* __restrict__ slot_w,
                                              int* __restrict__ counts) {
  int e = blockIdx.x;
  int tid = threadIdx.x, lane = tid & 63, wave = tid >> 6;
  __shared__ int wtot[4];
  int running = 0;
  for (int base = 0; base < NTOK * 2; base += 256) {
    int i = base + tid;
    int match = (eidx[i] == e) ? 1 : 0;
    unsigned long long mb = __ballot(match);
    if (lane == 0) wtot[wave] = __popcll(mb);
    __syncthreads();
    int pre = 0;
    for (int w = 0; w < wave; ++w) pre += wtot[w];
    int tot = wtot[0] + wtot[1] + wtot[2] + wtot[3];
    if (match) {
      int pos = running + pre + __popcll(mb & ((1ull << lane) - 1ull));
      if (pos < CAP) {
        slot_tok[e * CAP + pos] = i >> 1;
        slot_w[e * CAP + pos] = ew[i];
      }
    }
    running += tot;
    __syncthreads();
  }
  if (tid == 0) counts[e] = running;
}

// aux = 0.01 * 16 * sum_e(mean_probs[e] * min(count,cap)/N); mean_probs = 512/N exactly
__global__ void k_aux(const int* __restrict__ counts, float* __restrict__ aux) {
  int s = 0;
#pragma unroll
  for (int e = 0; e < NE; ++e) s += min(counts[e], CAP);
  *aux = 0.01f * (float)s / (float)NTOK;
}

// ---------------- GEMM1: h = gelu(x[slot] @ W1[e] + b1[e]) -> bf16 ----------------
__global__ __launch_bounds__(256) void k_gemm1(const float* __restrict__ x,
                                               const float* __restrict__ W1,
                                               const float* __restrict__ b1,
                                               const int* __restrict__ slot_tok,
                                               ushort_t* __restrict__ hbuf) {
  int e = blockIdx.z;
  int n0 = blockIdx.x * 64;
  int m0 = blockIdx.y * 64;
  __shared__ float As[16][64];
  __shared__ float Bs[16][64];
  const float* B = W1 + (size_t)e * DM * HD;
  int tid = threadIdx.x;
  int ar = tid >> 2, ak = (tid & 3) * 4;
  int br = tid >> 4, bn = (tid & 15) * 4;
  int tok = slot_tok[e * CAP + m0 + ar];
  const float* arow = (tok >= 0) ? (x + (size_t)tok * DM) : nullptr;
  int tm = (tid >> 4) * 4, tn = (tid & 15) * 4;
  float acc[4][4] = {};
  for (int k0 = 0; k0 < DM; k0 += 16) {
    float4 av = make_float4(0.f, 0.f, 0.f, 0.f);
    if (arow) av = *(const float4*)(arow + k0 + ak);
    float4 bv = *(const float4*)(B + (size_t)(k0 + br) * HD + n0 + bn);
    __syncthreads();
    As[ak + 0][ar] = av.x; As[ak + 1][ar] = av.y; As[ak + 2][ar] = av.z; As[ak + 3][ar] = av.w;
    *(float4*)&Bs[br][bn] = bv;
    __syncthreads();
#pragma unroll
    for (int kk = 0; kk < 16; ++kk) {
      float4 aq = *(const float4*)&As[kk][tm];
      float4 bq = *(const float4*)&Bs[kk][tn];
      acc[0][0] = fmaf(aq.x, bq.x, acc[0][0]); acc[0][1] = fmaf(aq.x, bq.y, acc[0][1]);
      acc[0][2] = fmaf(aq.x, bq.z, acc[0][2]); acc[0][3] = fmaf(aq.x, bq.w, acc[0][3]);
      acc[1][0] = fmaf(aq.y, bq.x, acc[1][0]); acc[1][1] = fmaf(aq.y, bq.y, acc[1][1]);
      acc[1][2] = fmaf(aq.y, bq.z, acc[1][2]); acc[1][3] = fmaf(aq.y, bq.w, acc[1][3]);
      acc[2][0] = fmaf(aq.z, bq.x, acc[2][0]); acc[2][1] = fmaf(aq.z, bq.y, acc[2][1]);
      acc[2][2] = fmaf(aq.z, bq.z, acc[2][2]); acc[2][3] = fmaf(aq.z, bq.w, acc[2][3]);
      acc[3][0] = fmaf(aq.w, bq.x, acc[3][0]); acc[3][1] = fmaf(aq.w, bq.y, acc[3][1]);
      acc[3][2] = fmaf(aq.w, bq.z, acc[3][2]); acc[3][3] = fmaf(aq.w, bq.w, acc[3][3]);
    }
  }
  const float* bb = b1 + (size_t)e * HD + n0 + tn;
  float bias[4] = { bb[0], bb[1], bb[2], bb[3] };
#pragma unroll
  for (int i = 0; i < 4; ++i) {
    ushort4 pk;
    float r[4];
#pragma unroll
    for (int j = 0; j < 4; ++j) {
      float v = acc[i][j] + bias[j];
      v = 0.5f * v * (1.0f + erff(v * 0.70710678118654752f));
      r[j] = v;
    }
    pk.x = f2bf(r[0]); pk.y = f2bf(r[1]); pk.z = f2bf(r[2]); pk.w = f2bf(r[3]);
    *(ushort4*)(hbuf + ((size_t)e * CAP + m0 + tm + i) * HD + n0 + tn) = pk;
  }
}

// -------- GEMM2: out = h @ W2[e] + b2[e]; scatter y[tok] += w*out (atomic, <=2 adds/elem) --------
__global__ __launch_bounds__(256) void k_gemm2(const ushort_t* __restrict__ hbuf,
                                               const float* __restrict__ W2,
                                               const float* __restrict__ b2,
                                               const int* __restrict__ slot_tok,
                                               const float* __restrict__ slot_w,
                                               float* __restrict__ y) {
  int e = blockIdx.z;
  int n0 = blockIdx.x * 64;
  int m0 = blockIdx.y * 64;
  __shared__ float As[16][64];
  __shared__ float Bs[16][64];
  const float* B = W2 + (size_t)e * HD * DM;
  int tid = threadIdx.x;
  int ar = tid >> 2, ak = (tid & 3) * 4;
  int br = tid >> 4, bn = (tid & 15) * 4;
  const ushort_t* arow = hbuf + ((size_t)e * CAP + m0 + ar) * HD;
  int tm = (tid >> 4) * 4, tn = (tid & 15) * 4;
  float acc[4][4] = {};
  for (int k0 = 0; k0 < HD; k0 += 16) {
    ushort4 av = *(const ushort4*)(arow + k0 + ak);
    float4 bv = *(const float4*)(B + (size_t)(k0 + br) * DM + n0 + bn);
    __syncthreads();
    As[ak + 0][ar] = bf2f(av.x); As[ak + 1][ar] = bf2f(av.y);
    As[ak + 2][ar] = bf2f(av.z); As[ak + 3][ar] = bf2f(av.w);
    *(float4*)&Bs[br][bn] = bv;
    __syncthreads();
#pragma unroll
    for (int kk = 0; kk < 16; ++kk) {
      float4 aq = *(const float4*)&As[kk][tm];
      float4 bq = *(const float4*)&Bs[kk][tn];
      acc[0][0] = fmaf(aq.x, bq.x, acc[0][0]); acc[0][1] = fmaf(aq.x, bq.y, acc[0][1]);
      acc[0][2] = fmaf(aq.x, bq.z, acc[0][2]); acc[0][3] = fmaf(aq.x, bq.w, acc[0][3]);
      acc[1][0] = fmaf(aq.y, bq.x, acc[1][0]); acc[1][1] = fmaf(aq.y, bq.y, acc[1][1]);
      acc[1][2] = fmaf(aq.y, bq.z, acc[1][2]); acc[1][3] = fmaf(aq.y, bq.w, acc[1][3]);
      acc[2][0] = fmaf(aq.z, bq.x, acc[2][0]); acc[2][1] = fmaf(aq.z, bq.y, acc[2][1]);
      acc[2][2] = fmaf(aq.z, bq.z, acc[2][2]); acc[2][3] = fmaf(aq.z, bq.w, acc[2][3]);
      acc[3][0] = fmaf(aq.w, bq.x, acc[3][0]); acc[3][1] = fmaf(aq.w, bq.y, acc[3][1]);
      acc[3][2] = fmaf(aq.w, bq.z, acc[3][2]); acc[3][3] = fmaf(aq.w, bq.w, acc[3][3]);
    }
  }
  const float* bb = b2 + (size_t)e * DM + n0 + tn;
  float bias[4] = { bb[0], bb[1], bb[2], bb[3] };
#pragma unroll
  for (int i = 0; i < 4; ++i) {
    int srow = m0 + tm + i;
    int tk = slot_tok[e * CAP + srow];
    if (tk >= 0) {
      float w = slot_w[e * CAP + srow];
#pragma unroll
      for (int j = 0; j < 4; ++j) {
        atomicAdd(&y[(size_t)tk * DM + n0 + tn + j], w * (acc[i][j] + bias[j]));
      }
    }
  }
}

extern "C" void kernel_launch(void* const* d_in, const int* in_sizes, int n_in,
                              void* d_out, int out_size, void* d_ws, size_t ws_size,
                              hipStream_t stream) {
  const float* x  = (const float*)d_in[0];
  const float* Wr = (const float*)d_in[1];
  const float* W1 = (const float*)d_in[2];
  const float* b1 = (const float*)d_in[3];
  const float* W2 = (const float*)d_in[4];
  const float* b2 = (const float*)d_in[5];
  float* y = (float*)d_out;
  float* aux = y + (size_t)NTOK * DM;

  char* ws = (char*)d_ws;
  float* probs    = (float*)ws; ws += (size_t)NTOK * NE * 4;   // 512 KB
  float* partial  = (float*)ws; ws += 32 * NE * 4;
  float* cs       = (float*)ws; ws += 256;
  int*   eidx     = (int*)ws;   ws += NTOK * 2 * 4;
  float* ew       = (float*)ws; ws += NTOK * 2 * 4;
  int*   slot_tok = (int*)ws;   ws += NE * CAP * 4;
  float* slot_w   = (float*)ws; ws += NE * CAP * 4;
  int*   counts   = (int*)ws;   ws += 256;
  ushort_t* hbuf  = (ushort_t*)ws;                             // 16*640*4096*2 = 80 MB

  hipMemsetAsync(d_out, 0, (size_t)out_size * 4, stream);
  hipMemsetAsync(slot_tok, 0xFF, (size_t)NE * CAP * 4, stream);

  k_router<<<NTOK / 4, 256, 0, stream>>>(x, Wr, probs);
  for (int it = 0; it < 3; ++it) {
    k_rownorm<<<32, 256, 0, stream>>>(probs, partial);
    k_colreduce<<<1, 64, 0, stream>>>(partial, cs);
    k_colscale<<<32, 256, 0, stream>>>(probs, cs);
  }
  k_topk<<<32, 256, 0, stream>>>(probs, eidx, ew);
  k_scan<<<NE, 256, 0, stream>>>(eidx, ew, slot_tok, slot_w, counts);
  k_aux<<<1, 1, 0, stream>>>(counts, aux);

  dim3 g1(HD / 64, CAP / 64, NE);
  k_gemm1<<<g1, 256, 0, stream>>>(x, W1, b1, slot_tok, hbuf);
  dim3 g2(DM / 64, CAP / 64, NE);
  k_gemm2<<<g2, 256, 0, stream>>>(hbuf, W2, b2, slot_tok, slot_w, y);
}

// Round 2
// 646.487 us; speedup vs baseline: 3.5164x; 3.5164x over previous
//
#include <hip/hip_runtime.h>
#include <hip/hip_bf16.h>
#include <math.h>

#define NTOK 8192
#define DM   1024
#define NE   16
#define HD   4096
#define CAP  640

typedef float f32x4 __attribute__((ext_vector_type(4)));
typedef _Float16 f16x8 __attribute__((ext_vector_type(8)));
typedef _Float16 f16x4 __attribute__((ext_vector_type(4)));

__device__ __forceinline__ void gload16(const void* g, void* l) {
  __builtin_amdgcn_global_load_lds(
      (const __attribute__((address_space(1))) unsigned int*)g,
      (__attribute__((address_space(3))) unsigned int*)l, 16, 0, 0);
}

// ---------------- router: logits + softmax + col partials (one wave/token) ----------------
__global__ __launch_bounds__(256) void k_router(const float* __restrict__ x,
                                                const float* __restrict__ Wr,
                                                float* __restrict__ probs,
                                                float* __restrict__ pout) {
  int wave = threadIdx.x >> 6, lane = threadIdx.x & 63;
  int tok = blockIdx.x * 4 + wave;
  const float* xr = x + (size_t)tok * DM;
  float acc[NE];
#pragma unroll
  for (int e = 0; e < NE; ++e) acc[e] = 0.f;
  for (int d = lane; d < DM; d += 64) {
    float xv = xr[d];
    const float* w = Wr + (size_t)d * NE;
#pragma unroll
    for (int e = 0; e < NE; ++e) acc[e] = fmaf(xv, w[e], acc[e]);
  }
#pragma unroll
  for (int off = 32; off >= 1; off >>= 1) {
#pragma unroll
    for (int e = 0; e < NE; ++e) acc[e] += __shfl_xor(acc[e], off, 64);
  }
  float m = acc[0];
#pragma unroll
  for (int e = 1; e < NE; ++e) m = fmaxf(m, acc[e]);
  float s = 0.f;
#pragma unroll
  for (int e = 0; e < NE; ++e) { acc[e] = expf(acc[e] - m); s += acc[e]; }
  float inv = 1.0f / s;
#pragma unroll
  for (int e = 0; e < NE; ++e) acc[e] *= inv;
  if (lane < NE) probs[(size_t)tok * NE + lane] = acc[lane];
  __shared__ float wsum[4][NE];
  if (lane == 0) {
#pragma unroll
    for (int e = 0; e < NE; ++e) wsum[wave][e] = acc[e];
  }
  __syncthreads();
  if (threadIdx.x < NE)
    pout[blockIdx.x * NE + threadIdx.x] =
        wsum[0][threadIdx.x] + wsum[1][threadIdx.x] + wsum[2][threadIdx.x] + wsum[3][threadIdx.x];
}

// ------------- fused sinkhorn step: col-normalize, row-normalize, emit col partials -------------
__global__ __launch_bounds__(256) void k_sink(float* __restrict__ probs,
                                              const float* __restrict__ pin,
                                              float* __restrict__ pout) {
  __shared__ float csinv[NE];
  int tid = threadIdx.x;
  if (tid < NE) {
    float s = 0.f;
#pragma unroll
    for (int b = 0; b < 32; ++b) s += pin[b * NE + tid];
    csinv[tid] = 512.0f / s;
  }
  __syncthreads();
  int tok = blockIdx.x * 256 + tid;
  float* row = probs + (size_t)tok * NE;
  float p[NE]; float rs = 0.f;
#pragma unroll
  for (int e = 0; e < NE; ++e) { p[e] = row[e] * csinv[e]; rs += p[e]; }
  float rinv = 1.0f / rs;
#pragma unroll
  for (int e = 0; e < NE; ++e) { p[e] *= rinv; row[e] = p[e]; }
#pragma unroll
  for (int off = 32; off >= 1; off >>= 1) {
#pragma unroll
    for (int e = 0; e < NE; ++e) p[e] += __shfl_xor(p[e], off, 64);
  }
  __shared__ float wsum[4][NE];
  int lane = tid & 63, wave = tid >> 6;
  if (lane == 0) {
#pragma unroll
    for (int e = 0; e < NE; ++e) wsum[wave][e] = p[e];
  }
  __syncthreads();
  if (tid < NE)
    pout[blockIdx.x * NE + tid] =
        wsum[0][tid] + wsum[1][tid] + wsum[2][tid] + wsum[3][tid];
}

// ------------- final sinkhorn col-normalize fused with top-2 + weight renorm -------------
__global__ __launch_bounds__(256) void k_sink3(const float* __restrict__ probs,
                                               const float* __restrict__ pin,
                                               int* __restrict__ eidx,
                                               float* __restrict__ ew) {
  __shared__ float csinv[NE];
  int tid = threadIdx.x;
  if (tid < NE) {
    float s = 0.f;
#pragma unroll
    for (int b = 0; b < 32; ++b) s += pin[b * NE + tid];
    csinv[tid] = 512.0f / s;
  }
  __syncthreads();
  int tok = blockIdx.x * 256 + tid;
  const float* row = probs + (size_t)tok * NE;
  float v0 = -1e30f, v1 = -1e30f; int e0 = 0, e1 = 0;
#pragma unroll
  for (int e = 0; e < NE; ++e) {
    float v = row[e] * csinv[e];
    if (v > v0) { v1 = v0; e1 = e0; v0 = v; e0 = e; }
    else if (v > v1) { v1 = v; e1 = e; }
  }
  float s = v0 + v1;
  eidx[tok * 2] = e0; eidx[tok * 2 + 1] = e1;
  ew[tok * 2] = v0 / s; ew[tok * 2 + 1] = v1 / s;
}

// ------------- sequential (t,k)-order slot allocation: one block per expert -------------
__global__ __launch_bounds__(256) void k_scan(const int* __restrict__ eidx,
                                              const float* __restrict__ ew,
                                              int* __restrict__ slot_tok,
                                              float* __restrict__ slot_w,
                                              int* __restrict__ counts) {
  int e = blockIdx.x;
  int tid = threadIdx.x, lane = tid & 63, wave = tid >> 6;
  __shared__ int wtot[4];
  int running = 0;
  for (int base = 0; base < NTOK * 2; base += 256) {
    int i = base + tid;
    int match = (eidx[i] == e) ? 1 : 0;
    unsigned long long mb = __ballot(match);
    if (lane == 0) wtot[wave] = __popcll(mb);
    __syncthreads();
    int pre = 0;
    for (int w = 0; w < wave; ++w) pre += wtot[w];
    int tot = wtot[0] + wtot[1] + wtot[2] + wtot[3];
    if (match) {
      int pos = running + pre + __popcll(mb & ((1ull << lane) - 1ull));
      if (pos < CAP) {
        slot_tok[e * CAP + pos] = i >> 1;
        slot_w[e * CAP + pos] = ew[i];
      }
    }
    running += tot;
    __syncthreads();
  }
  if (tid == 0) counts[e] = running;
}

__global__ void k_aux(const int* __restrict__ counts, float* __restrict__ aux) {
  int s = 0;
#pragma unroll
  for (int e = 0; e < NE; ++e) s += min(counts[e], CAP);
  *aux = 0.01f * (float)s / (float)NTOK;
}

// ------------- gather expert inputs to fp16 (zero-fill unused slots) -------------
__global__ __launch_bounds__(256) void k_gather(const float* __restrict__ x,
                                                const int* __restrict__ slot_tok,
                                                _Float16* __restrict__ xg) {
  int row = blockIdx.x;
  int tok = slot_tok[row];
  int t = threadIdx.x;
  f16x4 h;
  if (tok >= 0) {
    float4 v = *(const float4*)(x + (size_t)tok * DM + t * 4);
    h[0] = (_Float16)v.x; h[1] = (_Float16)v.y; h[2] = (_Float16)v.z; h[3] = (_Float16)v.w;
  } else {
    h[0] = (_Float16)0.f; h[1] = (_Float16)0.f; h[2] = (_Float16)0.f; h[3] = (_Float16)0.f;
  }
  *(f16x4*)(xg + (size_t)row * DM + t * 4) = h;
}

// ------------- transpose+convert: W[e][K][N] fp32 -> WT[e][N][K] fp16 -------------
__global__ __launch_bounds__(256) void k_transpose(const float* __restrict__ W,
                                                   _Float16* __restrict__ WT,
                                                   int K, int N) {
  __shared__ float tile[64][65];
  int e = blockIdx.z;
  int n0 = blockIdx.x * 64, k0 = blockIdx.y * 64;
  const float* src = W + ((size_t)e * K + k0) * N + n0;
  int t = threadIdx.x;
  int kr = t >> 4, nc = (t & 15) * 4;
#pragma unroll
  for (int r = 0; r < 4; ++r) {
    int row = r * 16 + kr;
    float4 v = *(const float4*)(src + (size_t)row * N + nc);
    tile[row][nc + 0] = v.x; tile[row][nc + 1] = v.y;
    tile[row][nc + 2] = v.z; tile[row][nc + 3] = v.w;
  }
  __syncthreads();
  int nr = t >> 3, kc = (t & 7) * 8;
  size_t dstbase = ((size_t)e * N + n0) * (size_t)K + k0;
#pragma unroll
  for (int r = 0; r < 2; ++r) {
    int n = r * 32 + nr;
    f16x8 h;
#pragma unroll
    for (int j = 0; j < 8; ++j) h[j] = (_Float16)tile[kc + j][n];
    *(f16x8*)(WT + dstbase + (size_t)n * K + kc) = h;
  }
}

// ==================== fp16 MFMA GEMMs: 128x128 tile, BK=64, 4 waves ====================
// LDS tile layout: [128 rows][64 k] fp16, 16B chunks XOR-swizzled: chunk c stored at c^(row&7).
// global_load_lds writes linearly (lane*16B), so the GLOBAL source address is pre-swizzled.

__device__ __forceinline__ void stage_tile(const _Float16* gbase, int ld, int k0,
                                           _Float16* lds, int w, int lane) {
#pragma unroll
  for (int i = 0; i < 4; ++i) {
    int ci = (w * 4 + i) * 64 + lane;      // linear 16B-chunk id, 0..1023
    int row = ci >> 3, c = ci & 7;
    int cs = c ^ (row & 7);
    gload16(gbase + (size_t)row * ld + k0 + cs * 8, lds + (w * 4 + i) * 512);
  }
}

__global__ __launch_bounds__(256) void k_gemm1(const _Float16* __restrict__ xg,
                                               const _Float16* __restrict__ W1T,
                                               const float* __restrict__ b1,
                                               _Float16* __restrict__ hbuf) {
  int bid = blockIdx.x;                      // 2560 blocks
  int logical = (bid & 7) * 320 + (bid >> 3);
  int my = logical % 5;
  int nx = (logical / 5) % 32;
  int e  = logical / 160;
  int m0 = my * 128, n0 = nx * 128;
  __shared__ _Float16 As[128 * 64];
  __shared__ _Float16 Bs[128 * 64];
  const _Float16* Ab = xg  + ((size_t)e * CAP + m0) * DM;
  const _Float16* Bb = W1T + ((size_t)e * HD  + n0) * DM;
  int tid = threadIdx.x, lane = tid & 63, w = tid >> 6;
  int wr = w >> 1, wc = w & 1;
  int lr = lane & 15, kg = lane >> 4;

  f32x4 zero = {0.f, 0.f, 0.f, 0.f};
  f32x4 acc[4][4];
#pragma unroll
  for (int m = 0; m < 4; ++m)
#pragma unroll
    for (int n = 0; n < 4; ++n) acc[m][n] = zero;

  for (int k0 = 0; k0 < DM; k0 += 64) {
    __syncthreads();
    stage_tile(Ab, DM, k0, As, w, lane);
    stage_tile(Bb, DM, k0, Bs, w, lane);
    __syncthreads();
#pragma unroll
    for (int ks = 0; ks < 2; ++ks) {
      f16x8 af[4], bf[4];
#pragma unroll
      for (int m = 0; m < 4; ++m) {
        int row = wr * 64 + m * 16 + lr;
        int cs = (ks * 4 + kg) ^ (row & 7);
        af[m] = *(const f16x8*)(As + row * 64 + cs * 8);
      }
#pragma unroll
      for (int n = 0; n < 4; ++n) {
        int row = wc * 64 + n * 16 + lr;
        int cs = (ks * 4 + kg) ^ (row & 7);
        bf[n] = *(const f16x8*)(Bs + row * 64 + cs * 8);
      }
#pragma unroll
      for (int m = 0; m < 4; ++m)
#pragma unroll
        for (int n = 0; n < 4; ++n)
          acc[m][n] = __builtin_amdgcn_mfma_f32_16x16x32_f16(af[m], bf[n], acc[m][n], 0, 0, 0);
    }
  }
  // epilogue: bias + exact GELU -> fp16 h
  int lq = lane >> 4;
#pragma unroll
  for (int n = 0; n < 4; ++n) {
    int col = n0 + wc * 64 + n * 16 + lr;
    float bias = b1[(size_t)e * HD + col];
#pragma unroll
    for (int m = 0; m < 4; ++m) {
#pragma unroll
      for (int r = 0; r < 4; ++r) {
        int rowg = m0 + wr * 64 + m * 16 + lq * 4 + r;
        float v = acc[m][n][r] + bias;
        v = 0.5f * v * (1.0f + erff(v * 0.70710678118654752f));
        hbuf[((size_t)e * CAP + rowg) * HD + col] = (_Float16)v;
      }
    }
  }
}

__global__ __launch_bounds__(256) void k_gemm2(const _Float16* __restrict__ hbuf,
                                               const _Float16* __restrict__ W2T,
                                               const float* __restrict__ b2,
                                               const int* __restrict__ slot_tok,
                                               const float* __restrict__ slot_w,
                                               float* __restrict__ y) {
  int bid = blockIdx.x;                      // 640 blocks
  int logical = (bid & 7) * 80 + (bid >> 3);
  int my = logical % 5;
  int nx = (logical / 5) % 8;
  int e  = logical / 40;
  int m0 = my * 128, n0 = nx * 128;
  __shared__ _Float16 As[128 * 64];
  __shared__ _Float16 Bs[128 * 64];
  const _Float16* Ab = hbuf + ((size_t)e * CAP + m0) * HD;
  const _Float16* Bb = W2T  + ((size_t)e * DM  + n0) * HD;
  int tid = threadIdx.x, lane = tid & 63, w = tid >> 6;
  int wr = w >> 1, wc = w & 1;
  int lr = lane & 15, kg = lane >> 4;

  f32x4 zero = {0.f, 0.f, 0.f, 0.f};
  f32x4 acc[4][4];
#pragma unroll
  for (int m = 0; m < 4; ++m)
#pragma unroll
    for (int n = 0; n < 4; ++n) acc[m][n] = zero;

  for (int k0 = 0; k0 < HD; k0 += 64) {
    __syncthreads();
    stage_tile(Ab, HD, k0, As, w, lane);
    stage_tile(Bb, HD, k0, Bs, w, lane);
    __syncthreads();
#pragma unroll
    for (int ks = 0; ks < 2; ++ks) {
      f16x8 af[4], bf[4];
#pragma unroll
      for (int m = 0; m < 4; ++m) {
        int row = wr * 64 + m * 16 + lr;
        int cs = (ks * 4 + kg) ^ (row & 7);
        af[m] = *(const f16x8*)(As + row * 64 + cs * 8);
      }
#pragma unroll
      for (int n = 0; n < 4; ++n) {
        int row = wc * 64 + n * 16 + lr;
        int cs = (ks * 4 + kg) ^ (row & 7);
        bf[n] = *(const f16x8*)(Bs + row * 64 + cs * 8);
      }
#pragma unroll
      for (int m = 0; m < 4; ++m)
#pragma unroll
        for (int n = 0; n < 4; ++n)
          acc[m][n] = __builtin_amdgcn_mfma_f32_16x16x32_f16(af[m], bf[n], acc[m][n], 0, 0, 0);
    }
  }
  // epilogue: bias, gate weight, atomic scatter-combine (<=2 adds per y element)
  int lq = lane >> 4;
  float bias[4];
#pragma unroll
  for (int n = 0; n < 4; ++n)
    bias[n] = b2[(size_t)e * DM + n0 + wc * 64 + n * 16 + lr];
#pragma unroll
  for (int m = 0; m < 4; ++m) {
#pragma unroll
    for (int r = 0; r < 4; ++r) {
      int rowg = m0 + wr * 64 + m * 16 + lq * 4 + r;
      int slot = e * CAP + rowg;
      int tk = slot_tok[slot];
      if (tk >= 0) {
        float wgt = slot_w[slot];
#pragma unroll
        for (int n = 0; n < 4; ++n) {
          int col = n0 + wc * 64 + n * 16 + lr;
          atomicAdd(&y[(size_t)tk * DM + col], wgt * (acc[m][n][r] + bias[n]));
        }
      }
    }
  }
}

extern "C" void kernel_launch(void* const* d_in, const int* in_sizes, int n_in,
                              void* d_out, int out_size, void* d_ws, size_t ws_size,
                              hipStream_t stream) {
  const float* x  = (const float*)d_in[0];
  const float* Wr = (const float*)d_in[1];
  const float* W1 = (const float*)d_in[2];
  const float* b1 = (const float*)d_in[3];
  const float* W2 = (const float*)d_in[4];
  const float* b2 = (const float*)d_in[5];
  float* y = (float*)d_out;
  float* aux = y + (size_t)out_size - 1;

  char* ws = (char*)d_ws;
  float* probs    = (float*)ws; ws += (size_t)NTOK * NE * 4;   // 512 KB
  float* P0       = (float*)ws; ws += 32 * NE * 4;
  float* P1       = (float*)ws; ws += 32 * NE * 4;
  int*   eidx     = (int*)ws;   ws += NTOK * 2 * 4;
  float* ew       = (float*)ws; ws += NTOK * 2 * 4;
  int*   slot_tok = (int*)ws;   ws += NE * CAP * 4;
  float* slot_w   = (float*)ws; ws += NE * CAP * 4;
  int*   counts   = (int*)ws;   ws += 256;
  _Float16* xg    = (_Float16*)ws; ws += (size_t)NE * CAP * DM * 2;   // 20 MB
  _Float16* hbuf  = (_Float16*)ws; ws += (size_t)NE * CAP * HD * 2;   // 80 MB
  _Float16* WT    = (_Float16*)ws;                                    // 128 MB (shared W1T/W2T)

  hipMemsetAsync(d_out, 0, (size_t)out_size * 4, stream);
  hipMemsetAsync(slot_tok, 0xFF, (size_t)NE * CAP * 4, stream);

  k_router<<<NTOK / 4, 256, 0, stream>>>(x, Wr, probs, P0);
  k_sink<<<32, 256, 0, stream>>>(probs, P0, P1);
  k_sink<<<32, 256, 0, stream>>>(probs, P1, P0);
  k_sink3<<<32, 256, 0, stream>>>(probs, P0, eidx, ew);
  k_scan<<<NE, 256, 0, stream>>>(eidx, ew, slot_tok, slot_w, counts);
  k_aux<<<1, 1, 0, stream>>>(counts, aux);
  k_gather<<<NE * CAP, 256, 0, stream>>>(x, slot_tok, xg);

  dim3 t1(HD / 64, DM / 64, NE);
  k_transpose<<<t1, 256, 0, stream>>>(W1, WT, DM, HD);
  k_gemm1<<<2560, 256, 0, stream>>>(xg, WT, b1, hbuf);

  dim3 t2(DM / 64, HD / 64, NE);
  k_transpose<<<t2, 256, 0, stream>>>(W2, WT, HD, DM);
  k_gemm2<<<640, 256, 0, stream>>>(hbuf, WT, b2, slot_tok, slot_w, y);
}

// Round 3
// 591.003 us; speedup vs baseline: 3.8465x; 1.0939x over previous
//
#include <hip/hip_runtime.h>
#include <hip/hip_bf16.h>
#include <math.h>

#define NTOK 8192
#define DM   1024
#define NE   16
#define HD   4096
#define CAP  640

typedef float f32x4 __attribute__((ext_vector_type(4)));
typedef _Float16 f16x8 __attribute__((ext_vector_type(8)));
typedef _Float16 f16x4 __attribute__((ext_vector_type(4)));

__device__ __forceinline__ void gload16(const void* g, void* l) {
  __builtin_amdgcn_global_load_lds(
      (const __attribute__((address_space(1))) unsigned int*)g,
      (__attribute__((address_space(3))) unsigned int*)l, 16, 0, 0);
}

// ---------------- router: logits + softmax + col partials (one wave/token) ----------------
__global__ __launch_bounds__(256) void k_router(const float* __restrict__ x,
                                                const float* __restrict__ Wr,
                                                float* __restrict__ probs,
                                                float* __restrict__ pout) {
  int wave = threadIdx.x >> 6, lane = threadIdx.x & 63;
  int tok = blockIdx.x * 4 + wave;
  const float* xr = x + (size_t)tok * DM;
  float acc[NE];
#pragma unroll
  for (int e = 0; e < NE; ++e) acc[e] = 0.f;
  for (int d = lane; d < DM; d += 64) {
    float xv = xr[d];
    const float* w = Wr + (size_t)d * NE;
#pragma unroll
    for (int e = 0; e < NE; ++e) acc[e] = fmaf(xv, w[e], acc[e]);
  }
#pragma unroll
  for (int off = 32; off >= 1; off >>= 1) {
#pragma unroll
    for (int e = 0; e < NE; ++e) acc[e] += __shfl_xor(acc[e], off, 64);
  }
  float m = acc[0];
#pragma unroll
  for (int e = 1; e < NE; ++e) m = fmaxf(m, acc[e]);
  float s = 0.f;
#pragma unroll
  for (int e = 0; e < NE; ++e) { acc[e] = expf(acc[e] - m); s += acc[e]; }
  float inv = 1.0f / s;
#pragma unroll
  for (int e = 0; e < NE; ++e) acc[e] *= inv;
  if (lane < NE) probs[(size_t)tok * NE + lane] = acc[lane];
  __shared__ float wsum[4][NE];
  if (lane == 0) {
#pragma unroll
    for (int e = 0; e < NE; ++e) wsum[wave][e] = acc[e];
  }
  __syncthreads();
  if (threadIdx.x < NE)
    pout[blockIdx.x * NE + threadIdx.x] =
        wsum[0][threadIdx.x] + wsum[1][threadIdx.x] + wsum[2][threadIdx.x] + wsum[3][threadIdx.x];
}

// ------------- fused sinkhorn step: col-normalize, row-normalize, emit col partials -------------
__global__ __launch_bounds__(256) void k_sink(float* __restrict__ probs,
                                              const float* __restrict__ pin,
                                              float* __restrict__ pout) {
  __shared__ float csinv[NE];
  int tid = threadIdx.x;
  if (tid < NE) {
    float s = 0.f;
#pragma unroll
    for (int b = 0; b < 32; ++b) s += pin[b * NE + tid];
    csinv[tid] = 512.0f / s;
  }
  __syncthreads();
  int tok = blockIdx.x * 256 + tid;
  float* row = probs + (size_t)tok * NE;
  float p[NE]; float rs = 0.f;
#pragma unroll
  for (int e = 0; e < NE; ++e) { p[e] = row[e] * csinv[e]; rs += p[e]; }
  float rinv = 1.0f / rs;
#pragma unroll
  for (int e = 0; e < NE; ++e) { p[e] *= rinv; row[e] = p[e]; }
#pragma unroll
  for (int off = 32; off >= 1; off >>= 1) {
#pragma unroll
    for (int e = 0; e < NE; ++e) p[e] += __shfl_xor(p[e], off, 64);
  }
  __shared__ float wsum[4][NE];
  int lane = tid & 63, wave = tid >> 6;
  if (lane == 0) {
#pragma unroll
    for (int e = 0; e < NE; ++e) wsum[wave][e] = p[e];
  }
  __syncthreads();
  if (tid < NE)
    pout[blockIdx.x * NE + tid] =
        wsum[0][tid] + wsum[1][tid] + wsum[2][tid] + wsum[3][tid];
}

// ------------- final sinkhorn col-normalize fused with top-2 + weight renorm -------------
__global__ __launch_bounds__(256) void k_sink3(const float* __restrict__ probs,
                                               const float* __restrict__ pin,
                                               int* __restrict__ eidx,
                                               float* __restrict__ ew) {
  __shared__ float csinv[NE];
  int tid = threadIdx.x;
  if (tid < NE) {
    float s = 0.f;
#pragma unroll
    for (int b = 0; b < 32; ++b) s += pin[b * NE + tid];
    csinv[tid] = 512.0f / s;
  }
  __syncthreads();
  int tok = blockIdx.x * 256 + tid;
  const float* row = probs + (size_t)tok * NE;
  float v0 = -1e30f, v1 = -1e30f; int e0 = 0, e1 = 0;
#pragma unroll
  for (int e = 0; e < NE; ++e) {
    float v = row[e] * csinv[e];
    if (v > v0) { v1 = v0; e1 = e0; v0 = v; e0 = e; }
    else if (v > v1) { v1 = v; e1 = e; }
  }
  float s = v0 + v1;
  eidx[tok * 2] = e0; eidx[tok * 2 + 1] = e1;
  ew[tok * 2] = v0 / s; ew[tok * 2 + 1] = v1 / s;
}

// ------------- sequential (t,k)-order slot allocation: one block per expert -------------
__global__ __launch_bounds__(256) void k_scan(const int* __restrict__ eidx,
                                              const float* __restrict__ ew,
                                              int* __restrict__ slot_tok,
                                              float* __restrict__ slot_w,
                                              int* __restrict__ counts) {
  int e = blockIdx.x;
  int tid = threadIdx.x, lane = tid & 63, wave = tid >> 6;
  __shared__ int wtot[4];
  int running = 0;
  for (int base = 0; base < NTOK * 2; base += 256) {
    int i = base + tid;
    int match = (eidx[i] == e) ? 1 : 0;
    unsigned long long mb = __ballot(match);
    if (lane == 0) wtot[wave] = __popcll(mb);
    __syncthreads();
    int pre = 0;
    for (int w = 0; w < wave; ++w) pre += wtot[w];
    int tot = wtot[0] + wtot[1] + wtot[2] + wtot[3];
    if (match) {
      int pos = running + pre + __popcll(mb & ((1ull << lane) - 1ull));
      if (pos < CAP) {
        slot_tok[e * CAP + pos] = i >> 1;
        slot_w[e * CAP + pos] = ew[i];
      }
    }
    running += tot;
    __syncthreads();
  }
  if (tid == 0) counts[e] = running;
}

__global__ void k_aux(const int* __restrict__ counts, float* __restrict__ aux) {
  int s = 0;
#pragma unroll
  for (int e = 0; e < NE; ++e) s += min(counts[e], CAP);
  *aux = 0.01f * (float)s / (float)NTOK;
}

// ------------- gather expert inputs to fp16 (zero-fill unused slots) -------------
__global__ __launch_bounds__(256) void k_gather(const float* __restrict__ x,
                                                const int* __restrict__ slot_tok,
                                                _Float16* __restrict__ xg) {
  int row = blockIdx.x;
  int tok = slot_tok[row];
  int t = threadIdx.x;
  f16x4 h;
  if (tok >= 0) {
    float4 v = *(const float4*)(x + (size_t)tok * DM + t * 4);
    h[0] = (_Float16)v.x; h[1] = (_Float16)v.y; h[2] = (_Float16)v.z; h[3] = (_Float16)v.w;
  } else {
    h[0] = (_Float16)0.f; h[1] = (_Float16)0.f; h[2] = (_Float16)0.f; h[3] = (_Float16)0.f;
  }
  *(f16x4*)(xg + (size_t)row * DM + t * 4) = h;
}

// ------------- transpose+convert: W[e][K][N] fp32 -> WT[e][N][K] fp16 -------------
__global__ __launch_bounds__(256) void k_transpose(const float* __restrict__ W,
                                                   _Float16* __restrict__ WT,
                                                   int K, int N) {
  __shared__ float tile[64][65];
  int e = blockIdx.z;
  int n0 = blockIdx.x * 64, k0 = blockIdx.y * 64;
  const float* src = W + ((size_t)e * K + k0) * N + n0;
  int t = threadIdx.x;
  int kr = t >> 4, nc = (t & 15) * 4;
#pragma unroll
  for (int r = 0; r < 4; ++r) {
    int row = r * 16 + kr;
    float4 v = *(const float4*)(src + (size_t)row * N + nc);
    tile[row][nc + 0] = v.x; tile[row][nc + 1] = v.y;
    tile[row][nc + 2] = v.z; tile[row][nc + 3] = v.w;
  }
  __syncthreads();
  int nr = t >> 3, kc = (t & 7) * 8;
  size_t dstbase = ((size_t)e * N + n0) * (size_t)K + k0;
#pragma unroll
  for (int r = 0; r < 2; ++r) {
    int n = r * 32 + nr;
    f16x8 h;
#pragma unroll
    for (int j = 0; j < 8; ++j) h[j] = (_Float16)tile[kc + j][n];
    *(f16x8*)(WT + dstbase + (size_t)n * K + kc) = h;
  }
}

// ==================== fp16 MFMA GEMMs ====================
// LDS tile layout: [ROWS][64 k] fp16, 16B chunks XOR-swizzled: chunk c stored at c^(row&7).
// global_load_lds writes linearly (lane*16B), so the GLOBAL source address is pre-swizzled.

template<int ROWS>
__device__ __forceinline__ void stage_tile(const _Float16* gbase, int ld, int k0,
                                           _Float16* lds, int w, int lane) {
  constexpr int PER = (ROWS * 8) / 256;   // 16B chunks per thread
#pragma unroll
  for (int i = 0; i < PER; ++i) {
    int ci = (w * PER + i) * 64 + lane;
    int row = ci >> 3, c = ci & 7;
    int cs = c ^ (row & 7);
    gload16(gbase + (size_t)row * ld + k0 + cs * 8, lds + (w * PER + i) * 512);
  }
}

// ---- GEMM1: h = gelu(xg @ W1T^T + b1), 128x128 tile, bounce epilogue ----
__global__ __launch_bounds__(256) void k_gemm1(const _Float16* __restrict__ xg,
                                               const _Float16* __restrict__ W1T,
                                               const float* __restrict__ b1,
                                               _Float16* __restrict__ hbuf) {
  int bid = blockIdx.x;                      // 2560 blocks
  int logical = (bid & 7) * 320 + (bid >> 3);
  int my = logical % 5;
  int nx = (logical / 5) % 32;
  int e  = logical / 160;
  int m0 = my * 128, n0 = nx * 128;
  __shared__ _Float16 smem[2 * 128 * 64];    // As | Bs, reused as 128x128 bounce
  _Float16* As = smem;
  _Float16* Bs = smem + 128 * 64;
  const _Float16* Ab = xg  + ((size_t)e * CAP + m0) * DM;
  const _Float16* Bb = W1T + ((size_t)e * HD  + n0) * DM;
  int tid = threadIdx.x, lane = tid & 63, w = tid >> 6;
  int wr = w >> 1, wc = w & 1;
  int lr = lane & 15, kg = lane >> 4;

  f32x4 zero = {0.f, 0.f, 0.f, 0.f};
  f32x4 acc[4][4];
#pragma unroll
  for (int m = 0; m < 4; ++m)
#pragma unroll
    for (int n = 0; n < 4; ++n) acc[m][n] = zero;

  for (int k0 = 0; k0 < DM; k0 += 64) {
    __syncthreads();
    stage_tile<128>(Ab, DM, k0, As, w, lane);
    stage_tile<128>(Bb, DM, k0, Bs, w, lane);
    __syncthreads();
#pragma unroll
    for (int ks = 0; ks < 2; ++ks) {
      f16x8 af[4], bf[4];
#pragma unroll
      for (int m = 0; m < 4; ++m) {
        int row = wr * 64 + m * 16 + lr;
        int cs = (ks * 4 + kg) ^ (row & 7);
        af[m] = *(const f16x8*)(As + row * 64 + cs * 8);
      }
#pragma unroll
      for (int n = 0; n < 4; ++n) {
        int row = wc * 64 + n * 16 + lr;
        int cs = (ks * 4 + kg) ^ (row & 7);
        bf[n] = *(const f16x8*)(Bs + row * 64 + cs * 8);
      }
#pragma unroll
      for (int m = 0; m < 4; ++m)
#pragma unroll
        for (int n = 0; n < 4; ++n)
          acc[m][n] = __builtin_amdgcn_mfma_f32_16x16x32_f16(af[m], bf[n], acc[m][n], 0, 0, 0);
    }
  }
  // epilogue: bias + exact GELU -> fp16, bounce via LDS for coalesced stores
  __syncthreads();
  _Float16* Cb = smem;   // 128 x 128, col XOR-swizzled by ((row>>2)&3)<<4
  int lq = lane >> 4;
#pragma unroll
  for (int n = 0; n < 4; ++n) {
    int col = wc * 64 + n * 16 + lr;
    float bias = b1[(size_t)e * HD + n0 + col];
#pragma unroll
    for (int m = 0; m < 4; ++m) {
#pragma unroll
      for (int r = 0; r < 4; ++r) {
        int row = wr * 64 + m * 16 + lq * 4 + r;
        float v = acc[m][n][r] + bias;
        v = 0.5f * v * (1.0f + erff(v * 0.70710678118654752f));
        Cb[row * 128 + (col ^ (((row >> 2) & 3) << 4))] = (_Float16)v;
      }
    }
  }
  __syncthreads();
  int rr = tid >> 4;
  int c8 = (tid & 15) * 8;
#pragma unroll
  for (int p = 0; p < 8; ++p) {
    int row = p * 16 + rr;
    int colx = c8 ^ (((row >> 2) & 3) << 4);
    f16x8 v = *(const f16x8*)(Cb + row * 128 + colx);
    *(f16x8*)(hbuf + ((size_t)e * CAP + m0 + row) * HD + n0 + c8) = v;
  }
}

// ---- GEMM2: y[tok] += w * (h @ W2T^T + b2), 64x128 tile, 1280 blocks ----
__global__ __launch_bounds__(256) void k_gemm2(const _Float16* __restrict__ hbuf,
                                               const _Float16* __restrict__ W2T,
                                               const float* __restrict__ b2,
                                               const int* __restrict__ slot_tok,
                                               const float* __restrict__ slot_w,
                                               float* __restrict__ y) {
  int bid = blockIdx.x;                      // 1280 blocks
  int logical = (bid & 7) * 160 + (bid >> 3);
  int my = logical % 10;
  int nx = (logical / 10) % 8;
  int e  = logical / 80;
  int m0 = my * 64, n0 = nx * 128;
  __shared__ _Float16 As[64 * 64];
  __shared__ _Float16 Bs[128 * 64];
  const _Float16* Ab = hbuf + ((size_t)e * CAP + m0) * HD;
  const _Float16* Bb = W2T  + ((size_t)e * DM  + n0) * HD;
  int tid = threadIdx.x, lane = tid & 63, w = tid >> 6;
  int wm = w >> 1, wn = w & 1;
  int lr = lane & 15, kg = lane >> 4;

  f32x4 zero = {0.f, 0.f, 0.f, 0.f};
  f32x4 acc[2][4];
#pragma unroll
  for (int m = 0; m < 2; ++m)
#pragma unroll
    for (int n = 0; n < 4; ++n) acc[m][n] = zero;

  for (int k0 = 0; k0 < HD; k0 += 64) {
    __syncthreads();
    stage_tile<64>(Ab, HD, k0, As, w, lane);
    stage_tile<128>(Bb, HD, k0, Bs, w, lane);
    __syncthreads();
#pragma unroll
    for (int ks = 0; ks < 2; ++ks) {
      f16x8 af[2], bf[4];
#pragma unroll
      for (int m = 0; m < 2; ++m) {
        int row = wm * 32 + m * 16 + lr;
        int cs = (ks * 4 + kg) ^ (row & 7);
        af[m] = *(const f16x8*)(As + row * 64 + cs * 8);
      }
#pragma unroll
      for (int n = 0; n < 4; ++n) {
        int row = wn * 64 + n * 16 + lr;
        int cs = (ks * 4 + kg) ^ (row & 7);
        bf[n] = *(const f16x8*)(Bs + row * 64 + cs * 8);
      }
#pragma unroll
      for (int m = 0; m < 2; ++m)
#pragma unroll
        for (int n = 0; n < 4; ++n)
          acc[m][n] = __builtin_amdgcn_mfma_f32_16x16x32_f16(af[m], bf[n], acc[m][n], 0, 0, 0);
    }
  }
  // epilogue: bias, gate weight, atomic scatter-combine (<=2 adds per y element)
  int lq = lane >> 4;
  float bias[4];
#pragma unroll
  for (int n = 0; n < 4; ++n)
    bias[n] = b2[(size_t)e * DM + n0 + wn * 64 + n * 16 + lr];
#pragma unroll
  for (int m = 0; m < 2; ++m) {
#pragma unroll
    for (int r = 0; r < 4; ++r) {
      int rowg = m0 + wm * 32 + m * 16 + lq * 4 + r;
      int slot = e * CAP + rowg;
      int tk = slot_tok[slot];
      if (tk >= 0) {
        float wgt = slot_w[slot];
#pragma unroll
        for (int n = 0; n < 4; ++n) {
          int col = n0 + wn * 64 + n * 16 + lr;
          atomicAdd(&y[(size_t)tk * DM + col], wgt * (acc[m][n][r] + bias[n]));
        }
      }
    }
  }
}

extern "C" void kernel_launch(void* const* d_in, const int* in_sizes, int n_in,
                              void* d_out, int out_size, void* d_ws, size_t ws_size,
                              hipStream_t stream) {
  const float* x  = (const float*)d_in[0];
  const float* Wr = (const float*)d_in[1];
  const float* W1 = (const float*)d_in[2];
  const float* b1 = (const float*)d_in[3];
  const float* W2 = (const float*)d_in[4];
  const float* b2 = (const float*)d_in[5];
  float* y = (float*)d_out;
  float* aux = y + (size_t)out_size - 1;

  char* ws = (char*)d_ws;
  float* probs    = (float*)ws; ws += (size_t)NTOK * NE * 4;   // 512 KB
  float* P0       = (float*)ws; ws += 32 * NE * 4;
  float* P1       = (float*)ws; ws += 32 * NE * 4;
  int*   eidx     = (int*)ws;   ws += NTOK * 2 * 4;
  float* ew       = (float*)ws; ws += NTOK * 2 * 4;
  int*   slot_tok = (int*)ws;   ws += NE * CAP * 4;
  float* slot_w   = (float*)ws; ws += NE * CAP * 4;
  int*   counts   = (int*)ws;   ws += 256;
  _Float16* xg    = (_Float16*)ws; ws += (size_t)NE * CAP * DM * 2;   // 20 MB
  _Float16* hbuf  = (_Float16*)ws; ws += (size_t)NE * CAP * HD * 2;   // 80 MB
  _Float16* WT    = (_Float16*)ws;                                    // 128 MB (shared W1T/W2T)

  hipMemsetAsync(d_out, 0, (size_t)out_size * 4, stream);
  hipMemsetAsync(slot_tok, 0xFF, (size_t)NE * CAP * 4, stream);

  k_router<<<NTOK / 4, 256, 0, stream>>>(x, Wr, probs, P0);
  k_sink<<<32, 256, 0, stream>>>(probs, P0, P1);
  k_sink<<<32, 256, 0, stream>>>(probs, P1, P0);
  k_sink3<<<32, 256, 0, stream>>>(probs, P0, eidx, ew);
  k_scan<<<NE, 256, 0, stream>>>(eidx, ew, slot_tok, slot_w, counts);
  k_aux<<<1, 1, 0, stream>>>(counts, aux);
  k_gather<<<NE * CAP, 256, 0, stream>>>(x, slot_tok, xg);

  dim3 t1(HD / 64, DM / 64, NE);
  k_transpose<<<t1, 256, 0, stream>>>(W1, WT, DM, HD);
  k_gemm1<<<2560, 256, 0, stream>>>(xg, WT, b1, hbuf);

  dim3 t2(DM / 64, HD / 64, NE);
  k_transpose<<<t2, 256, 0, stream>>>(W2, WT, HD, DM);
  k_gemm2<<<1280, 256, 0, stream>>>(hbuf, WT, b2, slot_tok, slot_w, y);
}